// Round 1
// baseline (3770.830 us; speedup 1.0000x reference)
//
#include <hip/hip_runtime.h>

#define NN   40000
#define RR   16
#define EE   50000
#define DD   256
#define NB   4
#define KTOT (NB*DD + DD)   // 1280

// ws layout: v [NN][NB*DD] f32 (163,840,000 B) | deg [RR*NN] int (2,560,000 B)

__global__ __launch_bounds__(256) void k_deg(const int* __restrict__ edst,
                                             int* __restrict__ deg) {
    int e = blockIdx.x * blockDim.x + threadIdx.x;
    if (e >= RR * EE) return;
    int r = e / EE;
    atomicAdd(&deg[r * NN + edst[e]], 1);
}

__global__ __launch_bounds__(256) void k_scatter(const float* __restrict__ x,
                                                 const float* __restrict__ coeff,
                                                 const int* __restrict__ esrc,
                                                 const int* __restrict__ edst,
                                                 const int* __restrict__ deg,
                                                 float* __restrict__ v) {
    int gid  = blockIdx.x * blockDim.x + threadIdx.x;
    int w    = gid >> 6;          // one wave per edge
    int lane = gid & 63;
    if (w >= RR * EE) return;
    int r = w / EE;
    int s = esrc[w];
    int d = edst[w];
    float inv = 1.0f / (float)deg[r * NN + d];   // deg >= 1 for any dst with an edge
    float w0 = coeff[r * NB + 0] * inv;
    float w1 = coeff[r * NB + 1] * inv;
    float w2 = coeff[r * NB + 2] * inv;
    float w3 = coeff[r * NB + 3] * inv;
    const float* xr = x + (size_t)s * DD;
    float*       vr = v + (size_t)d * (NB * DD);
#pragma unroll
    for (int c = 0; c < 4; c++) {
        int j = c * 64 + lane;
        float xv = xr[j];
        __hip_atomic_fetch_add(vr + 0 * DD + j, w0 * xv, __ATOMIC_RELAXED, __HIP_MEMORY_SCOPE_AGENT);
        __hip_atomic_fetch_add(vr + 1 * DD + j, w1 * xv, __ATOMIC_RELAXED, __HIP_MEMORY_SCOPE_AGENT);
        __hip_atomic_fetch_add(vr + 2 * DD + j, w2 * xv, __ATOMIC_RELAXED, __HIP_MEMORY_SCOPE_AGENT);
        __hip_atomic_fetch_add(vr + 3 * DD + j, w3 * xv, __ATOMIC_RELAXED, __HIP_MEMORY_SCOPE_AGENT);
    }
}

// out[n][o] = relu( sum_k A[n][k] * Bcat[k][o] + bias[o] )
// A[n][k] = v[n][k] for k<1024, x[n][k-1024] otherwise
// Bcat[k][o] = bases[k*256+o] for k<1024 (b=k>>8, i=k&255), loop_weight otherwise
__global__ __launch_bounds__(256) void k_gemm(const float* __restrict__ v,
                                              const float* __restrict__ x,
                                              const float* __restrict__ bases,
                                              const float* __restrict__ lw,
                                              const float* __restrict__ bias,
                                              float* __restrict__ out) {
    __shared__ float As[64 * 36];   // 64 rows x 32 k, stride 36 (pad)
    __shared__ float Bs[32 * 260];  // 32 k x 256 cols, stride 260 (pad)
    int tid = threadIdx.x;
    int rowbase = blockIdx.x * 64;
    int tr = (tid >> 6) * 16;       // 16 rows per thread
    int tc = (tid & 63) * 4;        // 4 cols per thread

    float acc[16][4];
#pragma unroll
    for (int i = 0; i < 16; i++)
#pragma unroll
        for (int c = 0; c < 4; c++) acc[i][c] = 0.0f;

    for (int kb = 0; kb < KTOT; kb += 32) {
        // stage A tile 64x32
#pragma unroll
        for (int e = tid; e < 64 * 32; e += 256) {
            int row = e >> 5, kk = e & 31;
            int k = kb + kk;
            int n = rowbase + row;
            float a = (k < NB * DD) ? v[(size_t)n * (NB * DD) + k]
                                    : x[(size_t)n * DD + (k - NB * DD)];
            As[row * 36 + kk] = a;
        }
        // stage B tile 32x256
#pragma unroll
        for (int e = tid; e < 32 * 256; e += 256) {
            int kk = e >> 8, col = e & 255;
            int k = kb + kk;
            float b = (k < NB * DD) ? bases[(size_t)k * DD + col]
                                    : lw[(size_t)(k - NB * DD) * DD + col];
            Bs[kk * 260 + col] = b;
        }
        __syncthreads();
#pragma unroll
        for (int kk = 0; kk < 32; kk += 4) {
            float4 b0 = *(const float4*)&Bs[(kk + 0) * 260 + tc];
            float4 b1 = *(const float4*)&Bs[(kk + 1) * 260 + tc];
            float4 b2 = *(const float4*)&Bs[(kk + 2) * 260 + tc];
            float4 b3 = *(const float4*)&Bs[(kk + 3) * 260 + tc];
#pragma unroll
            for (int i = 0; i < 16; i++) {
                float4 a = *(const float4*)&As[(tr + i) * 36 + kk];
                acc[i][0] += a.x * b0.x + a.y * b1.x + a.z * b2.x + a.w * b3.x;
                acc[i][1] += a.x * b0.y + a.y * b1.y + a.z * b2.y + a.w * b3.y;
                acc[i][2] += a.x * b0.z + a.y * b1.z + a.z * b2.z + a.w * b3.z;
                acc[i][3] += a.x * b0.w + a.y * b1.w + a.z * b2.w + a.w * b3.w;
            }
        }
        __syncthreads();
    }

    float4 bv = *(const float4*)&bias[tc];
#pragma unroll
    for (int i = 0; i < 16; i++) {
        int n = rowbase + tr + i;
        float4 o;
        o.x = fmaxf(acc[i][0] + bv.x, 0.0f);
        o.y = fmaxf(acc[i][1] + bv.y, 0.0f);
        o.z = fmaxf(acc[i][2] + bv.z, 0.0f);
        o.w = fmaxf(acc[i][3] + bv.w, 0.0f);
        *(float4*)&out[(size_t)n * DD + tc] = o;
    }
}

extern "C" void kernel_launch(void* const* d_in, const int* in_sizes, int n_in,
                              void* d_out, int out_size, void* d_ws, size_t ws_size,
                              hipStream_t stream) {
    const float* x     = (const float*)d_in[0];
    const float* bases = (const float*)d_in[1];
    const float* coeff = (const float*)d_in[2];
    const float* lw    = (const float*)d_in[3];
    const float* bias  = (const float*)d_in[4];
    const int*   esrc  = (const int*)d_in[5];
    const int*   edst  = (const int*)d_in[6];
    float* out = (float*)d_out;

    size_t v_bytes   = (size_t)NN * (NB * DD) * sizeof(float);
    size_t deg_bytes = (size_t)RR * NN * sizeof(int);
    float* v   = (float*)d_ws;
    int*   deg = (int*)((char*)d_ws + v_bytes);

    hipMemsetAsync(d_ws, 0, v_bytes + deg_bytes, stream);

    int ne = RR * EE;
    k_deg<<<(ne + 255) / 256, 256, 0, stream>>>(edst, deg);

    long long nthreads = (long long)ne * 64;
    k_scatter<<<(int)((nthreads + 255) / 256), 256, 0, stream>>>(x, coeff, esrc, edst, deg, v);

    k_gemm<<<NN / 64, 256, 0, stream>>>(v, x, bases, lw, bias, out);
}

// Round 2
// 1529.083 us; speedup vs baseline: 2.4661x; 2.4661x over previous
//
#include <hip/hip_runtime.h>

#define NN   40000
#define RR   16
#define EE   50000
#define DD   256
#define NB   4
#define KTOT (NB*DD + DD)   // 1280

// ws layout (bytes):
//   v       @ 0           NN*1024 f32   = 163,840,000
//   deg     @ 163,840,000 RR*NN  int    =   2,560,000
//   hist    @ 166,400,000 NN     int    =     160,000
//   offsets @ 166,560,016 (NN+1) int
//   cursor  @ 166,720,032 NN     int
//   recs    @ 166,880,048 RR*EE  u32    =   3,200,000

__global__ __launch_bounds__(256) void k_deg(const int* __restrict__ edst,
                                             int* __restrict__ deg,
                                             int* __restrict__ hist) {
    int e = blockIdx.x * blockDim.x + threadIdx.x;
    if (e >= RR * EE) return;
    int r = e / EE;
    int d = edst[e];
    atomicAdd(&deg[r * NN + d], 1);
    atomicAdd(&hist[d], 1);
}

// single-block exclusive scan of hist[NN] -> offsets[NN+1], cursor[NN]
__global__ __launch_bounds__(1024) void k_scan(const int* __restrict__ hist,
                                               int* __restrict__ offsets,
                                               int* __restrict__ cursor) {
    __shared__ int part[1024];
    int t = threadIdx.x;
    const int CH = 40;                      // 1024*40 >= NN
    int lo = t * CH, hi = min(lo + CH, NN);
    int mysum = 0;
    for (int i = lo; i < hi; i++) mysum += hist[i];
    part[t] = mysum;
    __syncthreads();
    for (int off = 1; off < 1024; off <<= 1) {
        int val = (t >= off) ? part[t - off] : 0;
        __syncthreads();
        part[t] += val;
        __syncthreads();
    }
    int run = part[t] - mysum;              // exclusive
    for (int i = lo; i < hi; i++) {
        offsets[i] = run;
        cursor[i] = run;
        run += hist[i];
    }
    if (t == 1023) offsets[NN] = part[1023];
}

__global__ __launch_bounds__(256) void k_escatter(const int* __restrict__ esrc,
                                                  const int* __restrict__ edst,
                                                  int* __restrict__ cursor,
                                                  unsigned int* __restrict__ recs) {
    int e = blockIdx.x * blockDim.x + threadIdx.x;
    if (e >= RR * EE) return;
    int r = e / EE;
    int d = edst[e];
    int pos = atomicAdd(&cursor[d], 1);
    recs[pos] = (unsigned int)esrc[e] | ((unsigned int)r << 16);
}

// one wave per dst node: v[n][b*256+j] = sum_e coeff[r_e,b]/deg[r_e,n] * x[src_e][j]
__global__ __launch_bounds__(256) void k_gather(const float* __restrict__ x,
                                                const float* __restrict__ coeff,
                                                const int* __restrict__ deg,
                                                const int* __restrict__ offsets,
                                                const unsigned int* __restrict__ recs,
                                                float* __restrict__ v) {
    int wave = blockIdx.x * 4 + (threadIdx.x >> 6);
    int lane = threadIdx.x & 63;
    if (wave >= NN) return;
    int n = wave;
    int beg = offsets[n], end = offsets[n + 1];
    float4 a0 = {0,0,0,0}, a1 = {0,0,0,0}, a2 = {0,0,0,0}, a3 = {0,0,0,0};
    for (int ei = beg; ei < end; ei++) {
        unsigned int rec = recs[ei];
        int src = (int)(rec & 0xFFFFu);
        int r   = (int)(rec >> 16);
        float inv = 1.0f / (float)deg[r * NN + n];
        float4 wc = *(const float4*)&coeff[r * NB];
        float w0 = wc.x * inv, w1 = wc.y * inv, w2 = wc.z * inv, w3 = wc.w * inv;
        float4 xv = *(const float4*)&x[(size_t)src * DD + lane * 4];
        a0.x += w0 * xv.x; a0.y += w0 * xv.y; a0.z += w0 * xv.z; a0.w += w0 * xv.w;
        a1.x += w1 * xv.x; a1.y += w1 * xv.y; a1.z += w1 * xv.z; a1.w += w1 * xv.w;
        a2.x += w2 * xv.x; a2.y += w2 * xv.y; a2.z += w2 * xv.z; a2.w += w2 * xv.w;
        a3.x += w3 * xv.x; a3.y += w3 * xv.y; a3.z += w3 * xv.z; a3.w += w3 * xv.w;
    }
    float* vr = v + (size_t)n * (NB * DD);
    *(float4*)&vr[0 * DD + lane * 4] = a0;
    *(float4*)&vr[1 * DD + lane * 4] = a1;
    *(float4*)&vr[2 * DD + lane * 4] = a2;
    *(float4*)&vr[3 * DD + lane * 4] = a3;
}

// out[n][o] = relu( sum_k A[n][k] * Bcat[k][o] + bias[o] ),  A = [v | x], Bcat = [bases ; lw]
__global__ __launch_bounds__(256) void k_gemm(const float* __restrict__ v,
                                              const float* __restrict__ x,
                                              const float* __restrict__ bases,
                                              const float* __restrict__ lw,
                                              const float* __restrict__ bias,
                                              float* __restrict__ out) {
    __shared__ float As[64 * 36];   // 64 rows x 32 k, stride 36 (pad)
    __shared__ float Bs[32 * 260];  // 32 k x 256 cols, stride 260 (pad)
    int tid = threadIdx.x;
    int rowbase = blockIdx.x * 64;
    int tr = (tid >> 6) * 16;       // 16 rows per thread
    int tc = (tid & 63) * 4;        // 4 cols per thread

    float acc[16][4];
#pragma unroll
    for (int i = 0; i < 16; i++)
#pragma unroll
        for (int c = 0; c < 4; c++) acc[i][c] = 0.0f;

    for (int kb = 0; kb < KTOT; kb += 32) {
#pragma unroll
        for (int e = tid; e < 64 * 32; e += 256) {
            int row = e >> 5, kk = e & 31;
            int k = kb + kk;
            int n = rowbase + row;
            float a = (k < NB * DD) ? v[(size_t)n * (NB * DD) + k]
                                    : x[(size_t)n * DD + (k - NB * DD)];
            As[row * 36 + kk] = a;
        }
#pragma unroll
        for (int e = tid; e < 32 * 256; e += 256) {
            int kk = e >> 8, col = e & 255;
            int k = kb + kk;
            float b = (k < NB * DD) ? bases[(size_t)k * DD + col]
                                    : lw[(size_t)(k - NB * DD) * DD + col];
            Bs[kk * 260 + col] = b;
        }
        __syncthreads();
#pragma unroll
        for (int kk = 0; kk < 32; kk += 4) {
            float4 b0 = *(const float4*)&Bs[(kk + 0) * 260 + tc];
            float4 b1 = *(const float4*)&Bs[(kk + 1) * 260 + tc];
            float4 b2 = *(const float4*)&Bs[(kk + 2) * 260 + tc];
            float4 b3 = *(const float4*)&Bs[(kk + 3) * 260 + tc];
#pragma unroll
            for (int i = 0; i < 16; i++) {
                float4 a = *(const float4*)&As[(tr + i) * 36 + kk];
                acc[i][0] += a.x * b0.x + a.y * b1.x + a.z * b2.x + a.w * b3.x;
                acc[i][1] += a.x * b0.y + a.y * b1.y + a.z * b2.y + a.w * b3.y;
                acc[i][2] += a.x * b0.z + a.y * b1.z + a.z * b2.z + a.w * b3.z;
                acc[i][3] += a.x * b0.w + a.y * b1.w + a.z * b2.w + a.w * b3.w;
            }
        }
        __syncthreads();
    }

    float4 bv = *(const float4*)&bias[tc];
#pragma unroll
    for (int i = 0; i < 16; i++) {
        int n = rowbase + tr + i;
        float4 o;
        o.x = fmaxf(acc[i][0] + bv.x, 0.0f);
        o.y = fmaxf(acc[i][1] + bv.y, 0.0f);
        o.z = fmaxf(acc[i][2] + bv.z, 0.0f);
        o.w = fmaxf(acc[i][3] + bv.w, 0.0f);
        *(float4*)&out[(size_t)n * DD + tc] = o;
    }
}

extern "C" void kernel_launch(void* const* d_in, const int* in_sizes, int n_in,
                              void* d_out, int out_size, void* d_ws, size_t ws_size,
                              hipStream_t stream) {
    const float* x     = (const float*)d_in[0];
    const float* bases = (const float*)d_in[1];
    const float* coeff = (const float*)d_in[2];
    const float* lw    = (const float*)d_in[3];
    const float* bias  = (const float*)d_in[4];
    const int*   esrc  = (const int*)d_in[5];
    const int*   edst  = (const int*)d_in[6];
    float* out = (float*)d_out;

    char* ws = (char*)d_ws;
    float*        v       = (float*)(ws);
    int*          deg     = (int*)(ws + 163840000);
    int*          hist    = (int*)(ws + 166400000);
    int*          offsets = (int*)(ws + 166560016);
    int*          cursor  = (int*)(ws + 166720032);
    unsigned int* recs    = (unsigned int*)(ws + 166880048);

    // zero deg + hist only (v/offsets/cursor/recs are fully overwritten)
    hipMemsetAsync(deg, 0, (size_t)RR * NN * sizeof(int) + 160016, stream);

    int ne = RR * EE;
    k_deg<<<(ne + 255) / 256, 256, 0, stream>>>(edst, deg, hist);
    k_scan<<<1, 1024, 0, stream>>>(hist, offsets, cursor);
    k_escatter<<<(ne + 255) / 256, 256, 0, stream>>>(esrc, edst, cursor, recs);
    k_gather<<<NN / 4, 256, 0, stream>>>(x, coeff, deg, offsets, recs, v);
    k_gemm<<<NN / 64, 256, 0, stream>>>(v, x, bases, lw, bias, out);
}

// Round 3
// 472.166 us; speedup vs baseline: 7.9862x; 3.2384x over previous
//
#include <hip/hip_runtime.h>

#define NN   40000
#define RR   16
#define EE   50000
#define DD   256
#define NB   4
#define KTOT (NB*DD + DD)   // 1280

typedef __bf16 bf16x8 __attribute__((ext_vector_type(8)));
typedef float  f32x4  __attribute__((ext_vector_type(4)));
typedef unsigned short ushort_t;

__device__ inline float bf2f(unsigned short u) {
    union { unsigned int i; float f; } c; c.i = ((unsigned int)u) << 16; return c.f;
}
__device__ inline unsigned short f2bf(float f) {
    unsigned int b = __builtin_bit_cast(unsigned int, f);
    b += 0x7FFFu + ((b >> 16) & 1u);      // round-to-nearest-even
    return (unsigned short)(b >> 16);
}

// ws layout (bytes), all 16B-aligned:
//   vb      @ 0            NN*1024 bf16 =  81,920,000
//   xb      @ 81,920,000   NN*256  bf16 =  20,480,000
//   Bt      @ 102,400,000  256*1280 bf16 =    655,360
//   deg     @ 103,055,360  RR*NN int    =   2,560,000
//   hist    @ 105,615,360  NN int       =     160,000
//   offsets @ 105,775,360  (NN+1) int
//   cursor  @ 105,935,376  NN int
//   recs    @ 106,095,376  RR*EE u32    =   3,200,000

__global__ __launch_bounds__(256) void k_xcast(const float* __restrict__ x,
                                               ushort_t* __restrict__ xb) {
    int t = blockIdx.x * blockDim.x + threadIdx.x;   // one thread per 4 elems
    if (t >= NN * DD / 4) return;
    float4 f = *(const float4*)(x + (size_t)t * 4);
    ushort4 o;
    o.x = f2bf(f.x); o.y = f2bf(f.y); o.z = f2bf(f.z); o.w = f2bf(f.w);
    *(ushort4*)(xb + (size_t)t * 4) = o;
}

// Bt[o][k] = bf16( k<1024 ? bases[k*256+o] : lw[(k-1024)*256+o] )
__global__ __launch_bounds__(256) void k_prep(const float* __restrict__ bases,
                                              const float* __restrict__ lw,
                                              ushort_t* __restrict__ Bt) {
    int t = blockIdx.x * blockDim.x + threadIdx.x;   // t = o*1280 + k
    if (t >= DD * KTOT) return;
    int o = t / KTOT, k = t - o * KTOT;
    float f = (k < NB * DD) ? bases[(size_t)k * DD + o]
                            : lw[(size_t)(k - NB * DD) * DD + o];
    Bt[t] = f2bf(f);
}

__global__ __launch_bounds__(256) void k_deg(const int* __restrict__ edst,
                                             int* __restrict__ deg,
                                             int* __restrict__ hist) {
    int e = blockIdx.x * blockDim.x + threadIdx.x;
    if (e >= RR * EE) return;
    int r = e / EE;
    int d = edst[e];
    atomicAdd(&deg[r * NN + d], 1);
    atomicAdd(&hist[d], 1);
}

__global__ __launch_bounds__(1024) void k_scan(const int* __restrict__ hist,
                                               int* __restrict__ offsets,
                                               int* __restrict__ cursor) {
    __shared__ int part[1024];
    int t = threadIdx.x;
    const int CH = 40;
    int lo = t * CH, hi = min(lo + CH, NN);
    int mysum = 0;
    for (int i = lo; i < hi; i++) mysum += hist[i];
    part[t] = mysum;
    __syncthreads();
    for (int off = 1; off < 1024; off <<= 1) {
        int val = (t >= off) ? part[t - off] : 0;
        __syncthreads();
        part[t] += val;
        __syncthreads();
    }
    int run = part[t] - mysum;
    for (int i = lo; i < hi; i++) {
        offsets[i] = run;
        cursor[i] = run;
        run += hist[i];
    }
    if (t == 1023) offsets[NN] = part[1023];
}

__global__ __launch_bounds__(256) void k_escatter(const int* __restrict__ esrc,
                                                  const int* __restrict__ edst,
                                                  int* __restrict__ cursor,
                                                  unsigned int* __restrict__ recs) {
    int e = blockIdx.x * blockDim.x + threadIdx.x;
    if (e >= RR * EE) return;
    int r = e / EE;
    int d = edst[e];
    int pos = atomicAdd(&cursor[d], 1);
    recs[pos] = (unsigned int)esrc[e] | ((unsigned int)r << 16);
}

// one wave per dst node; reads bf16 x, accumulates f32, writes bf16 v
__global__ __launch_bounds__(256) void k_gather(const ushort_t* __restrict__ xb,
                                                const float* __restrict__ coeff,
                                                const int* __restrict__ deg,
                                                const int* __restrict__ offsets,
                                                const unsigned int* __restrict__ recs,
                                                ushort_t* __restrict__ vb) {
    int wave = blockIdx.x * 4 + (threadIdx.x >> 6);
    int lane = threadIdx.x & 63;
    if (wave >= NN) return;
    int n = wave;
    int beg = offsets[n], end = offsets[n + 1];
    float4 a0 = {0,0,0,0}, a1 = {0,0,0,0}, a2 = {0,0,0,0}, a3 = {0,0,0,0};
    for (int ei = beg; ei < end; ei++) {
        unsigned int rec = recs[ei];
        int src = (int)(rec & 0xFFFFu);
        int r   = (int)(rec >> 16);
        float inv = 1.0f / (float)deg[r * NN + n];
        float4 wc = *(const float4*)&coeff[r * NB];
        float w0 = wc.x * inv, w1 = wc.y * inv, w2 = wc.z * inv, w3 = wc.w * inv;
        ushort4 xr = *(const ushort4*)(xb + (size_t)src * DD + lane * 4);
        float xv0 = bf2f(xr.x), xv1 = bf2f(xr.y), xv2 = bf2f(xr.z), xv3 = bf2f(xr.w);
        a0.x += w0 * xv0; a0.y += w0 * xv1; a0.z += w0 * xv2; a0.w += w0 * xv3;
        a1.x += w1 * xv0; a1.y += w1 * xv1; a1.z += w1 * xv2; a1.w += w1 * xv3;
        a2.x += w2 * xv0; a2.y += w2 * xv1; a2.z += w2 * xv2; a2.w += w2 * xv3;
        a3.x += w3 * xv0; a3.y += w3 * xv1; a3.z += w3 * xv2; a3.w += w3 * xv3;
    }
    ushort_t* vr = vb + (size_t)n * (NB * DD) + lane * 4;
    ushort4 o;
    o.x = f2bf(a0.x); o.y = f2bf(a0.y); o.z = f2bf(a0.z); o.w = f2bf(a0.w);
    *(ushort4*)(vr + 0 * DD) = o;
    o.x = f2bf(a1.x); o.y = f2bf(a1.y); o.z = f2bf(a1.z); o.w = f2bf(a1.w);
    *(ushort4*)(vr + 1 * DD) = o;
    o.x = f2bf(a2.x); o.y = f2bf(a2.y); o.z = f2bf(a2.z); o.w = f2bf(a2.w);
    *(ushort4*)(vr + 2 * DD) = o;
    o.x = f2bf(a3.x); o.y = f2bf(a3.y); o.z = f2bf(a3.z); o.w = f2bf(a3.w);
    *(ushort4*)(vr + 3 * DD) = o;
}

// MFMA GEMM: out[M=40000][256] = relu([vb | xb] @ Bt^T + bias)
// block tile 128x128, 4 waves 2x2, wave tile 64x64 (4x4 mfma 16x16x32)
#define LDA 40   // ushort stride, 80B rows: 16B aligned, 2-way bank alias only
__global__ __launch_bounds__(256) void k_gemm(const ushort_t* __restrict__ vb,
                                              const ushort_t* __restrict__ xb,
                                              const ushort_t* __restrict__ Bt,
                                              const float* __restrict__ bias,
                                              float* __restrict__ out) {
    __shared__ ushort_t As[128 * LDA];
    __shared__ ushort_t Bs[128 * LDA];
    int tid  = threadIdx.x;
    int lane = tid & 63;
    int w    = tid >> 6;
    int wr   = w >> 1, wc = w & 1;
    int rowbase = blockIdx.x * 128;
    int nbase   = blockIdx.y * 128;

    f32x4 acc[4][4];
#pragma unroll
    for (int i = 0; i < 4; i++)
#pragma unroll
        for (int j = 0; j < 4; j++) acc[i][j] = (f32x4){0,0,0,0};

    int m0 = wr * 64 + (lane & 15);
    int n0 = wc * 64 + (lane & 15);
    int kq = (lane >> 4) * 8;

    for (int kb = 0; kb < KTOT; kb += 32) {
        __syncthreads();
#pragma unroll
        for (int s = 0; s < 2; s++) {
            int e = s * 256 + tid;          // 0..511
            int row = e >> 2, ch = (e & 3) * 8;
            int node = min(rowbase + row, NN - 1);
            const ushort_t* asrc = (kb < NB * DD)
                ? vb + (size_t)node * (NB * DD) + kb + ch
                : xb + (size_t)node * DD + (kb - NB * DD) + ch;
            uint4 av = *(const uint4*)asrc;
            const ushort_t* bsrc = Bt + (size_t)(nbase + row) * KTOT + kb + ch;
            uint4 bv = *(const uint4*)bsrc;
            *(uint4*)&As[row * LDA + ch] = av;
            *(uint4*)&Bs[row * LDA + ch] = bv;
        }
        __syncthreads();

        bf16x8 af[4], bf[4];
#pragma unroll
        for (int i = 0; i < 4; i++)
            af[i] = *(const bf16x8*)&As[(m0 + i * 16) * LDA + kq];
#pragma unroll
        for (int j = 0; j < 4; j++)
            bf[j] = *(const bf16x8*)&Bs[(n0 + j * 16) * LDA + kq];
#pragma unroll
        for (int i = 0; i < 4; i++)
#pragma unroll
            for (int j = 0; j < 4; j++)
                acc[i][j] = __builtin_amdgcn_mfma_f32_16x16x32_bf16(af[i], bf[j], acc[i][j], 0, 0, 0);
    }

    // epilogue: C layout col=lane&15, row=(lane>>4)*4+reg
#pragma unroll
    for (int i = 0; i < 4; i++) {
#pragma unroll
        for (int r = 0; r < 4; r++) {
            int row = wr * 64 + i * 16 + (lane >> 4) * 4 + r;
            int ng = rowbase + row;
            if (ng >= NN) continue;
#pragma unroll
            for (int j = 0; j < 4; j++) {
                int o = nbase + wc * 64 + j * 16 + (lane & 15);
                float vv = acc[i][j][r] + bias[o];
                out[(size_t)ng * DD + o] = fmaxf(vv, 0.0f);
            }
        }
    }
}

extern "C" void kernel_launch(void* const* d_in, const int* in_sizes, int n_in,
                              void* d_out, int out_size, void* d_ws, size_t ws_size,
                              hipStream_t stream) {
    const float* x     = (const float*)d_in[0];
    const float* bases = (const float*)d_in[1];
    const float* coeff = (const float*)d_in[2];
    const float* lw    = (const float*)d_in[3];
    const float* bias  = (const float*)d_in[4];
    const int*   esrc  = (const int*)d_in[5];
    const int*   edst  = (const int*)d_in[6];
    float* out = (float*)d_out;

    char* ws = (char*)d_ws;
    ushort_t*     vb      = (ushort_t*)(ws);
    ushort_t*     xb      = (ushort_t*)(ws + 81920000);
    ushort_t*     Bt      = (ushort_t*)(ws + 102400000);
    int*          deg     = (int*)(ws + 103055360);
    int*          hist    = (int*)(ws + 105615360);
    int*          offsets = (int*)(ws + 105775360);
    int*          cursor  = (int*)(ws + 105935376);
    unsigned int* recs    = (unsigned int*)(ws + 106095376);

    // zero deg + hist only; everything else is fully overwritten each call
    hipMemsetAsync(deg, 0, (size_t)RR * NN * sizeof(int) + 160000, stream);

    int ne = RR * EE;
    k_xcast<<<(NN * DD / 4 + 255) / 256, 256, 0, stream>>>(x, xb);
    k_prep<<<(DD * KTOT + 255) / 256, 256, 0, stream>>>(bases, lw, Bt);
    k_deg<<<(ne + 255) / 256, 256, 0, stream>>>(edst, deg, hist);
    k_scan<<<1, 1024, 0, stream>>>(hist, offsets, cursor);
    k_escatter<<<(ne + 255) / 256, 256, 0, stream>>>(esrc, edst, cursor, recs);
    k_gather<<<NN / 4, 256, 0, stream>>>(xb, coeff, deg, offsets, recs, vb);
    dim3 ggrid((NN + 127) / 128, 2);
    k_gemm<<<ggrid, 256, 0, stream>>>(vb, xb, Bt, bias, out);
}

// Round 4
// 399.387 us; speedup vs baseline: 9.4415x; 1.1822x over previous
//
#include <hip/hip_runtime.h>

#define NN   40000
#define RR   16
#define EE   50000
#define DD   256
#define NB   4
#define KTOT (NB*DD + DD)   // 1280

typedef __bf16 bf16x8 __attribute__((ext_vector_type(8)));
typedef float  f32x4  __attribute__((ext_vector_type(4)));
typedef float  f32x2  __attribute__((ext_vector_type(2)));
typedef unsigned short ushort_t;

__device__ inline unsigned short f2bf(float f) {
    unsigned int b = __builtin_bit_cast(unsigned int, f);
    b += 0x7FFFu + ((b >> 16) & 1u);      // round-to-nearest-even
    return (unsigned short)(b >> 16);
}

// ws layout (bytes), all 16B-aligned:
//   vb      @ 0            NN*1024 bf16 =  81,920,000
//   xb      @ 81,920,000   NN*256  bf16 =  20,480,000
//   Bt      @ 102,400,000  256*1280 bf16 =    655,360
//   deg     @ 103,055,360  RR*NN int    =   2,560,000
//   hist    @ 105,615,360  NN int       =     160,000
//   offsets @ 105,775,360  (NN+1) int   (pad to 16)
//   cursor  @ 105,935,376  NN int
//   recs    @ 106,095,376  RR*EE u32    =   3,200,000

// fused: xb cast + Bt build
__global__ __launch_bounds__(256) void k_cast(const float* __restrict__ x,
                                              const float* __restrict__ bases,
                                              const float* __restrict__ lw,
                                              ushort_t* __restrict__ xb,
                                              ushort_t* __restrict__ Bt) {
    int t = blockIdx.x * blockDim.x + threadIdx.x;
    const int NX = NN * DD / 4;
    if (t < NX) {
        float4 f = *(const float4*)(x + (size_t)t * 4);
        ushort4 o;
        o.x = f2bf(f.x); o.y = f2bf(f.y); o.z = f2bf(f.z); o.w = f2bf(f.w);
        *(ushort4*)(xb + (size_t)t * 4) = o;
    } else {
        int u = t - NX;                    // u = o*1280 + k
        if (u < DD * KTOT) {
            int o = u / KTOT, k = u - o * KTOT;
            float f = (k < NB * DD) ? bases[(size_t)k * DD + o]
                                    : lw[(size_t)(k - NB * DD) * DD + o];
            Bt[u] = f2bf(f);
        }
    }
}

__global__ __launch_bounds__(256) void k_deg(const int* __restrict__ edst,
                                             int* __restrict__ deg) {
    int e = blockIdx.x * blockDim.x + threadIdx.x;
    if (e >= RR * EE) return;
    int r = e / EE;
    atomicAdd(&deg[r * NN + edst[e]], 1);
}

__global__ __launch_bounds__(256) void k_hist(const int* __restrict__ deg,
                                              int* __restrict__ hist) {
    int i = blockIdx.x * blockDim.x + threadIdx.x;
    if (i >= NN) return;
    int s = 0;
#pragma unroll
    for (int r = 0; r < RR; r++) s += deg[r * NN + i];
    hist[i] = s;
}

__global__ __launch_bounds__(1024) void k_scan(const int* __restrict__ hist,
                                               int* __restrict__ offsets,
                                               int* __restrict__ cursor) {
    __shared__ int part[1024];
    int t = threadIdx.x;
    const int CH = 40;
    int lo = t * CH, hi = min(lo + CH, NN);
    int mysum = 0;
    for (int i = lo; i < hi; i++) mysum += hist[i];
    part[t] = mysum;
    __syncthreads();
    for (int off = 1; off < 1024; off <<= 1) {
        int val = (t >= off) ? part[t - off] : 0;
        __syncthreads();
        part[t] += val;
        __syncthreads();
    }
    int run = part[t] - mysum;
    for (int i = lo; i < hi; i++) {
        offsets[i] = run;
        cursor[i] = run;
        run += hist[i];
    }
    if (t == 1023) offsets[NN] = part[1023];
}

__global__ __launch_bounds__(256) void k_escatter(const int* __restrict__ esrc,
                                                  const int* __restrict__ edst,
                                                  int* __restrict__ cursor,
                                                  unsigned int* __restrict__ recs) {
    int e = blockIdx.x * blockDim.x + threadIdx.x;
    if (e >= RR * EE) return;
    int r = e / EE;
    int d = edst[e];
    int pos = atomicAdd(&cursor[d], 1);
    recs[pos] = (unsigned int)esrc[e] | ((unsigned int)r << 16);
}

// one wave per dst node; per-wave weight table in LDS; 4-edge unrolled MLP
__global__ __launch_bounds__(256) void k_gather(const ushort_t* __restrict__ xb,
                                                const float* __restrict__ coeff,
                                                const int* __restrict__ deg,
                                                const int* __restrict__ offsets,
                                                const unsigned int* __restrict__ recs,
                                                ushort_t* __restrict__ vb) {
    __shared__ float wtab[4][64];
    int lane = threadIdx.x & 63;
    int wv   = threadIdx.x >> 6;
    int n    = __builtin_amdgcn_readfirstlane(blockIdx.x * 4 + wv);

    {   // wtab[wv][r*4+b] = coeff[r*4+b] / max(deg[r][n],1);  lane = r*4+b (NB==4)
        int r  = lane >> 2;
        int dg = deg[r * NN + n];
        float inv = 1.0f / (float)(dg > 0 ? dg : 1);
        wtab[wv][lane] = coeff[lane] * inv;
    }

    int beg = offsets[n], end = offsets[n + 1];
    f32x2 a[4][2];
#pragma unroll
    for (int b = 0; b < 4; b++) { a[b][0] = (f32x2){0,0}; a[b][1] = (f32x2){0,0}; }

    const float* wrow = &wtab[wv][0];
    const ushort_t* xl = xb + lane * 4;

    auto acc_edge = [&](uint2 u, float4 w) {
        f32x2 lo, hi;
        lo.x = __builtin_bit_cast(float, u.x << 16);
        lo.y = __builtin_bit_cast(float, u.x & 0xFFFF0000u);
        hi.x = __builtin_bit_cast(float, u.y << 16);
        hi.y = __builtin_bit_cast(float, u.y & 0xFFFF0000u);
        a[0][0] = lo * (f32x2){w.x, w.x} + a[0][0];
        a[0][1] = hi * (f32x2){w.x, w.x} + a[0][1];
        a[1][0] = lo * (f32x2){w.y, w.y} + a[1][0];
        a[1][1] = hi * (f32x2){w.y, w.y} + a[1][1];
        a[2][0] = lo * (f32x2){w.z, w.z} + a[2][0];
        a[2][1] = hi * (f32x2){w.z, w.z} + a[2][1];
        a[3][0] = lo * (f32x2){w.w, w.w} + a[3][0];
        a[3][1] = hi * (f32x2){w.w, w.w} + a[3][1];
    };

    int ei = beg;
    for (; ei + 4 <= end; ei += 4) {
        unsigned int r0 = recs[ei + 0];
        unsigned int r1 = recs[ei + 1];
        unsigned int r2 = recs[ei + 2];
        unsigned int r3 = recs[ei + 3];
        uint2 u0 = *(const uint2*)(xl + (size_t)(r0 & 0xFFFFu) * DD);
        uint2 u1 = *(const uint2*)(xl + (size_t)(r1 & 0xFFFFu) * DD);
        uint2 u2 = *(const uint2*)(xl + (size_t)(r2 & 0xFFFFu) * DD);
        uint2 u3 = *(const uint2*)(xl + (size_t)(r3 & 0xFFFFu) * DD);
        float4 w0 = *(const float4*)&wrow[(r0 >> 16) * 4];
        float4 w1 = *(const float4*)&wrow[(r1 >> 16) * 4];
        float4 w2 = *(const float4*)&wrow[(r2 >> 16) * 4];
        float4 w3 = *(const float4*)&wrow[(r3 >> 16) * 4];
        acc_edge(u0, w0);
        acc_edge(u1, w1);
        acc_edge(u2, w2);
        acc_edge(u3, w3);
    }
    for (; ei < end; ei++) {
        unsigned int r0 = recs[ei];
        uint2 u0 = *(const uint2*)(xl + (size_t)(r0 & 0xFFFFu) * DD);
        float4 w0 = *(const float4*)&wrow[(r0 >> 16) * 4];
        acc_edge(u0, w0);
    }

    ushort_t* vr = vb + (size_t)n * (NB * DD) + lane * 4;
#pragma unroll
    for (int b = 0; b < 4; b++) {
        ushort4 o;
        o.x = f2bf(a[b][0].x); o.y = f2bf(a[b][0].y);
        o.z = f2bf(a[b][1].x); o.w = f2bf(a[b][1].y);
        *(ushort4*)(vr + b * DD) = o;
    }
}

// MFMA GEMM: out[M=40000][256] = relu([vb | xb] @ Bt^T + bias)
#define LDA 40
__global__ __launch_bounds__(256) void k_gemm(const ushort_t* __restrict__ vb,
                                              const ushort_t* __restrict__ xb,
                                              const ushort_t* __restrict__ Bt,
                                              const float* __restrict__ bias,
                                              float* __restrict__ out) {
    __shared__ ushort_t As[128 * LDA];
    __shared__ ushort_t Bs[128 * LDA];
    int tid  = threadIdx.x;
    int lane = tid & 63;
    int w    = tid >> 6;
    int wr   = w >> 1, wc = w & 1;
    int rowbase = blockIdx.x * 128;
    int nbase   = blockIdx.y * 128;

    f32x4 acc[4][4];
#pragma unroll
    for (int i = 0; i < 4; i++)
#pragma unroll
        for (int j = 0; j < 4; j++) acc[i][j] = (f32x4){0,0,0,0};

    int m0 = wr * 64 + (lane & 15);
    int n0 = wc * 64 + (lane & 15);
    int kq = (lane >> 4) * 8;

    for (int kb = 0; kb < KTOT; kb += 32) {
        __syncthreads();
#pragma unroll
        for (int s = 0; s < 2; s++) {
            int e = s * 256 + tid;
            int row = e >> 2, ch = (e & 3) * 8;
            int node = min(rowbase + row, NN - 1);
            const ushort_t* asrc = (kb < NB * DD)
                ? vb + (size_t)node * (NB * DD) + kb + ch
                : xb + (size_t)node * DD + (kb - NB * DD) + ch;
            uint4 av = *(const uint4*)asrc;
            const ushort_t* bsrc = Bt + (size_t)(nbase + row) * KTOT + kb + ch;
            uint4 bv = *(const uint4*)bsrc;
            *(uint4*)&As[row * LDA + ch] = av;
            *(uint4*)&Bs[row * LDA + ch] = bv;
        }
        __syncthreads();

        bf16x8 af[4], bf[4];
#pragma unroll
        for (int i = 0; i < 4; i++)
            af[i] = *(const bf16x8*)&As[(m0 + i * 16) * LDA + kq];
#pragma unroll
        for (int j = 0; j < 4; j++)
            bf[j] = *(const bf16x8*)&Bs[(n0 + j * 16) * LDA + kq];
#pragma unroll
        for (int i = 0; i < 4; i++)
#pragma unroll
            for (int j = 0; j < 4; j++)
                acc[i][j] = __builtin_amdgcn_mfma_f32_16x16x32_bf16(af[i], bf[j], acc[i][j], 0, 0, 0);
    }

#pragma unroll
    for (int i = 0; i < 4; i++) {
#pragma unroll
        for (int r = 0; r < 4; r++) {
            int row = wr * 64 + i * 16 + (lane >> 4) * 4 + r;
            int ng = rowbase + row;
            if (ng >= NN) continue;
#pragma unroll
            for (int j = 0; j < 4; j++) {
                int o = nbase + wc * 64 + j * 16 + (lane & 15);
                float vv = acc[i][j][r] + bias[o];
                out[(size_t)ng * DD + o] = fmaxf(vv, 0.0f);
            }
        }
    }
}

extern "C" void kernel_launch(void* const* d_in, const int* in_sizes, int n_in,
                              void* d_out, int out_size, void* d_ws, size_t ws_size,
                              hipStream_t stream) {
    const float* x     = (const float*)d_in[0];
    const float* bases = (const float*)d_in[1];
    const float* coeff = (const float*)d_in[2];
    const float* lw    = (const float*)d_in[3];
    const float* bias  = (const float*)d_in[4];
    const int*   esrc  = (const int*)d_in[5];
    const int*   edst  = (const int*)d_in[6];
    float* out = (float*)d_out;

    char* ws = (char*)d_ws;
    ushort_t*     vb      = (ushort_t*)(ws);
    ushort_t*     xb      = (ushort_t*)(ws + 81920000);
    ushort_t*     Bt      = (ushort_t*)(ws + 102400000);
    int*          deg     = (int*)(ws + 103055360);
    int*          hist    = (int*)(ws + 105615360);
    int*          offsets = (int*)(ws + 105775360);
    int*          cursor  = (int*)(ws + 105935376);
    unsigned int* recs    = (unsigned int*)(ws + 106095376);

    hipMemsetAsync(deg, 0, (size_t)RR * NN * sizeof(int), stream);

    int ne = RR * EE;
    int ncast = NN * DD / 4 + DD * KTOT;
    k_cast<<<(ncast + 255) / 256, 256, 0, stream>>>(x, bases, lw, xb, Bt);
    k_deg<<<(ne + 255) / 256, 256, 0, stream>>>(edst, deg);
    k_hist<<<(NN + 255) / 256, 256, 0, stream>>>(deg, hist);
    k_scan<<<1, 1024, 0, stream>>>(hist, offsets, cursor);
    k_escatter<<<(ne + 255) / 256, 256, 0, stream>>>(esrc, edst, cursor, recs);
    k_gather<<<NN / 4, 256, 0, stream>>>(xb, coeff, deg, offsets, recs, vb);
    dim3 ggrid((NN + 127) / 128, 2);
    k_gemm<<<ggrid, 256, 0, stream>>>(vb, xb, Bt, bias, out);
}

// Round 5
// 320.267 us; speedup vs baseline: 11.7740x; 1.2470x over previous
//
#include <hip/hip_runtime.h>

#define NN   40000
#define RR   16
#define EE   50000
#define DD   256
#define NB   4
#define KTOT (NB*DD + DD)   // 1280

#define SCAN_BLK  40
#define SCAN_ELEM 1024      // elements per scan block (40*1024 >= NN)

typedef __bf16 bf16x8 __attribute__((ext_vector_type(8)));
typedef float  f32x4  __attribute__((ext_vector_type(4)));
typedef float  f32x2  __attribute__((ext_vector_type(2)));
typedef unsigned short ushort_t;

__device__ inline unsigned short f2bf(float f) {
    unsigned int b = __builtin_bit_cast(unsigned int, f);
    b += 0x7FFFu + ((b >> 16) & 1u);      // round-to-nearest-even
    return (unsigned short)(b >> 16);
}

// ws layout (bytes), all 16B-aligned:
//   vb      @ 0            NN*1024 bf16 =  81,920,000
//   xb      @ 81,920,000   NN*256  bf16 =  20,480,000
//   Bt      @ 102,400,000  256*1280 bf16 =    655,360
//   deg     @ 103,055,360  RR*NN int    =   2,560,000
//   hist    @ 105,615,360  NN int       =     160,000
//   offsets @ 105,775,360  (NN+1) int
//   cursor  @ 105,935,376  NN int
//   recs    @ 106,095,376  RR*EE u32    =   3,200,000
//   bsum    @ 109,295,376  SCAN_BLK int

// fused: xb cast + Bt build
__global__ __launch_bounds__(256) void k_cast(const float* __restrict__ x,
                                              const float* __restrict__ bases,
                                              const float* __restrict__ lw,
                                              ushort_t* __restrict__ xb,
                                              ushort_t* __restrict__ Bt) {
    int t = blockIdx.x * blockDim.x + threadIdx.x;
    const int NX = NN * DD / 4;
    if (t < NX) {
        float4 f = *(const float4*)(x + (size_t)t * 4);
        ushort4 o;
        o.x = f2bf(f.x); o.y = f2bf(f.y); o.z = f2bf(f.z); o.w = f2bf(f.w);
        *(ushort4*)(xb + (size_t)t * 4) = o;
    } else {
        int u = t - NX;                    // u = o*1280 + k
        if (u < DD * KTOT) {
            int o = u / KTOT, k = u - o * KTOT;
            float f = (k < NB * DD) ? bases[(size_t)k * DD + o]
                                    : lw[(size_t)(k - NB * DD) * DD + o];
            Bt[u] = f2bf(f);
        }
    }
}

__global__ __launch_bounds__(256) void k_deg(const int* __restrict__ edst,
                                             int* __restrict__ deg) {
    int e = blockIdx.x * blockDim.x + threadIdx.x;
    if (e >= RR * EE) return;
    int r = e / EE;
    atomicAdd(&deg[r * NN + edst[e]], 1);
}

__global__ __launch_bounds__(256) void k_hist(const int* __restrict__ deg,
                                              int* __restrict__ hist) {
    int i = blockIdx.x * blockDim.x + threadIdx.x;
    if (i >= NN) return;
    int s = 0;
#pragma unroll
    for (int r = 0; r < RR; r++) s += deg[r * NN + i];
    hist[i] = s;
}

// phase A: block-local exclusive scan of 1024 elems -> offsets, block sum -> bsum
__global__ __launch_bounds__(256) void k_scanA(const int* __restrict__ hist,
                                               int* __restrict__ offsets,
                                               int* __restrict__ bsum) {
    __shared__ int part[256];
    int t = threadIdx.x, b = blockIdx.x;
    int g = b * SCAN_ELEM + t * 4;
    int4 h = {0, 0, 0, 0};
    if (g + 3 < NN) h = *(const int4*)(hist + g);
    else {
        if (g + 0 < NN) h.x = hist[g + 0];
        if (g + 1 < NN) h.y = hist[g + 1];
        if (g + 2 < NN) h.z = hist[g + 2];
        if (g + 3 < NN) h.w = hist[g + 3];
    }
    int s = h.x + h.y + h.z + h.w;
    part[t] = s;
    __syncthreads();
    for (int off = 1; off < 256; off <<= 1) {
        int v = (t >= off) ? part[t - off] : 0;
        __syncthreads();
        part[t] += v;
        __syncthreads();
    }
    int ex = part[t] - s;
    int4 o;
    o.x = ex;
    o.y = ex + h.x;
    o.z = ex + h.x + h.y;
    o.w = ex + h.x + h.y + h.z;
    if (g + 3 < NN) *(int4*)(offsets + g) = o;
    else {
        if (g + 0 < NN) offsets[g + 0] = o.x;
        if (g + 1 < NN) offsets[g + 1] = o.y;
        if (g + 2 < NN) offsets[g + 2] = o.z;
        if (g + 3 < NN) offsets[g + 3] = o.w;
    }
    if (t == 255) bsum[b] = part[255];
}

// phase B: add block-prefix base, mirror into cursor, write offsets[NN]
__global__ __launch_bounds__(256) void k_scanB(const int* __restrict__ bsum,
                                               int* __restrict__ offsets,
                                               int* __restrict__ cursor) {
    __shared__ int sbase, stot;
    int t = threadIdx.x, b = blockIdx.x;
    if (t == 0) {
        int acc = 0, base = 0;
        for (int i = 0; i < SCAN_BLK; i++) {
            if (i == b) base = acc;
            acc += bsum[i];
        }
        sbase = base;
        stot = acc;
    }
    __syncthreads();
    int base = sbase;
    int g = b * SCAN_ELEM + t * 4;
    if (g + 3 < NN) {
        int4 o = *(const int4*)(offsets + g);
        o.x += base; o.y += base; o.z += base; o.w += base;
        *(int4*)(offsets + g) = o;
        *(int4*)(cursor + g) = o;
    } else {
#pragma unroll
        for (int c = 0; c < 4; c++) {
            if (g + c < NN) {
                int v = offsets[g + c] + base;
                offsets[g + c] = v;
                cursor[g + c] = v;
            }
        }
    }
    if (b == SCAN_BLK - 1 && t == 0) offsets[NN] = stot;
}

__global__ __launch_bounds__(256) void k_escatter(const int* __restrict__ esrc,
                                                  const int* __restrict__ edst,
                                                  int* __restrict__ cursor,
                                                  unsigned int* __restrict__ recs) {
    int e = blockIdx.x * blockDim.x + threadIdx.x;
    if (e >= RR * EE) return;
    int r = e / EE;
    int d = edst[e];
    int pos = atomicAdd(&cursor[d], 1);
    recs[pos] = (unsigned int)esrc[e] | ((unsigned int)r << 16);
}

// one wave per dst node; per-wave weight table in LDS; 4-edge unrolled MLP
__global__ __launch_bounds__(256) void k_gather(const ushort_t* __restrict__ xb,
                                                const float* __restrict__ coeff,
                                                const int* __restrict__ deg,
                                                const int* __restrict__ offsets,
                                                const unsigned int* __restrict__ recs,
                                                ushort_t* __restrict__ vb) {
    __shared__ float wtab[4][64];
    int lane = threadIdx.x & 63;
    int wv   = threadIdx.x >> 6;
    int n    = __builtin_amdgcn_readfirstlane(blockIdx.x * 4 + wv);

    {   // wtab[wv][r*4+b] = coeff[r*4+b] / max(deg[r][n],1);  lane = r*4+b (NB==4)
        int r  = lane >> 2;
        int dg = deg[r * NN + n];
        float inv = 1.0f / (float)(dg > 0 ? dg : 1);
        wtab[wv][lane] = coeff[lane] * inv;
    }

    int beg = offsets[n], end = offsets[n + 1];
    f32x2 a[4][2];
#pragma unroll
    for (int b = 0; b < 4; b++) { a[b][0] = (f32x2){0,0}; a[b][1] = (f32x2){0,0}; }

    const float* wrow = &wtab[wv][0];
    const ushort_t* xl = xb + lane * 4;

    auto acc_edge = [&](uint2 u, float4 w) {
        f32x2 lo, hi;
        lo.x = __builtin_bit_cast(float, u.x << 16);
        lo.y = __builtin_bit_cast(float, u.x & 0xFFFF0000u);
        hi.x = __builtin_bit_cast(float, u.y << 16);
        hi.y = __builtin_bit_cast(float, u.y & 0xFFFF0000u);
        a[0][0] = lo * (f32x2){w.x, w.x} + a[0][0];
        a[0][1] = hi * (f32x2){w.x, w.x} + a[0][1];
        a[1][0] = lo * (f32x2){w.y, w.y} + a[1][0];
        a[1][1] = hi * (f32x2){w.y, w.y} + a[1][1];
        a[2][0] = lo * (f32x2){w.z, w.z} + a[2][0];
        a[2][1] = hi * (f32x2){w.z, w.z} + a[2][1];
        a[3][0] = lo * (f32x2){w.w, w.w} + a[3][0];
        a[3][1] = hi * (f32x2){w.w, w.w} + a[3][1];
    };

    int ei = beg;
    for (; ei + 4 <= end; ei += 4) {
        unsigned int r0 = recs[ei + 0];
        unsigned int r1 = recs[ei + 1];
        unsigned int r2 = recs[ei + 2];
        unsigned int r3 = recs[ei + 3];
        uint2 u0 = *(const uint2*)(xl + (size_t)(r0 & 0xFFFFu) * DD);
        uint2 u1 = *(const uint2*)(xl + (size_t)(r1 & 0xFFFFu) * DD);
        uint2 u2 = *(const uint2*)(xl + (size_t)(r2 & 0xFFFFu) * DD);
        uint2 u3 = *(const uint2*)(xl + (size_t)(r3 & 0xFFFFu) * DD);
        float4 w0 = *(const float4*)&wrow[(r0 >> 16) * 4];
        float4 w1 = *(const float4*)&wrow[(r1 >> 16) * 4];
        float4 w2 = *(const float4*)&wrow[(r2 >> 16) * 4];
        float4 w3 = *(const float4*)&wrow[(r3 >> 16) * 4];
        acc_edge(u0, w0);
        acc_edge(u1, w1);
        acc_edge(u2, w2);
        acc_edge(u3, w3);
    }
    for (; ei < end; ei++) {
        unsigned int r0 = recs[ei];
        uint2 u0 = *(const uint2*)(xl + (size_t)(r0 & 0xFFFFu) * DD);
        float4 w0 = *(const float4*)&wrow[(r0 >> 16) * 4];
        acc_edge(u0, w0);
    }

    ushort_t* vr = vb + (size_t)n * (NB * DD) + lane * 4;
#pragma unroll
    for (int b = 0; b < 4; b++) {
        ushort4 o;
        o.x = f2bf(a[b][0].x); o.y = f2bf(a[b][0].y);
        o.z = f2bf(a[b][1].x); o.w = f2bf(a[b][1].y);
        *(ushort4*)(vr + b * DD) = o;
    }
}

// MFMA GEMM: out[M=40000][256] = relu([vb | xb] @ Bt^T + bias)
#define LDA 40
__global__ __launch_bounds__(256) void k_gemm(const ushort_t* __restrict__ vb,
                                              const ushort_t* __restrict__ xb,
                                              const ushort_t* __restrict__ Bt,
                                              const float* __restrict__ bias,
                                              float* __restrict__ out) {
    __shared__ ushort_t As[128 * LDA];
    __shared__ ushort_t Bs[128 * LDA];
    int tid  = threadIdx.x;
    int lane = tid & 63;
    int w    = tid >> 6;
    int wr   = w >> 1, wc = w & 1;
    int rowbase = blockIdx.x * 128;
    int nbase   = blockIdx.y * 128;

    f32x4 acc[4][4];
#pragma unroll
    for (int i = 0; i < 4; i++)
#pragma unroll
        for (int j = 0; j < 4; j++) acc[i][j] = (f32x4){0,0,0,0};

    int m0 = wr * 64 + (lane & 15);
    int n0 = wc * 64 + (lane & 15);
    int kq = (lane >> 4) * 8;

    for (int kb = 0; kb < KTOT; kb += 32) {
        __syncthreads();
#pragma unroll
        for (int s = 0; s < 2; s++) {
            int e = s * 256 + tid;
            int row = e >> 2, ch = (e & 3) * 8;
            int node = min(rowbase + row, NN - 1);
            const ushort_t* asrc = (kb < NB * DD)
                ? vb + (size_t)node * (NB * DD) + kb + ch
                : xb + (size_t)node * DD + (kb - NB * DD) + ch;
            uint4 av = *(const uint4*)asrc;
            const ushort_t* bsrc = Bt + (size_t)(nbase + row) * KTOT + kb + ch;
            uint4 bv = *(const uint4*)bsrc;
            *(uint4*)&As[row * LDA + ch] = av;
            *(uint4*)&Bs[row * LDA + ch] = bv;
        }
        __syncthreads();

        bf16x8 af[4], bf[4];
#pragma unroll
        for (int i = 0; i < 4; i++)
            af[i] = *(const bf16x8*)&As[(m0 + i * 16) * LDA + kq];
#pragma unroll
        for (int j = 0; j < 4; j++)
            bf[j] = *(const bf16x8*)&Bs[(n0 + j * 16) * LDA + kq];
#pragma unroll
        for (int i = 0; i < 4; i++)
#pragma unroll
            for (int j = 0; j < 4; j++)
                acc[i][j] = __builtin_amdgcn_mfma_f32_16x16x32_bf16(af[i], bf[j], acc[i][j], 0, 0, 0);
    }

#pragma unroll
    for (int i = 0; i < 4; i++) {
#pragma unroll
        for (int r = 0; r < 4; r++) {
            int row = wr * 64 + i * 16 + (lane >> 4) * 4 + r;
            int ng = rowbase + row;
            if (ng >= NN) continue;
#pragma unroll
            for (int j = 0; j < 4; j++) {
                int o = nbase + wc * 64 + j * 16 + (lane & 15);
                float vv = acc[i][j][r] + bias[o];
                out[(size_t)ng * DD + o] = fmaxf(vv, 0.0f);
            }
        }
    }
}

extern "C" void kernel_launch(void* const* d_in, const int* in_sizes, int n_in,
                              void* d_out, int out_size, void* d_ws, size_t ws_size,
                              hipStream_t stream) {
    const float* x     = (const float*)d_in[0];
    const float* bases = (const float*)d_in[1];
    const float* coeff = (const float*)d_in[2];
    const float* lw    = (const float*)d_in[3];
    const float* bias  = (const float*)d_in[4];
    const int*   esrc  = (const int*)d_in[5];
    const int*   edst  = (const int*)d_in[6];
    float* out = (float*)d_out;

    char* ws = (char*)d_ws;
    ushort_t*     vb      = (ushort_t*)(ws);
    ushort_t*     xb      = (ushort_t*)(ws + 81920000);
    ushort_t*     Bt      = (ushort_t*)(ws + 102400000);
    int*          deg     = (int*)(ws + 103055360);
    int*          hist    = (int*)(ws + 105615360);
    int*          offsets = (int*)(ws + 105775360);
    int*          cursor  = (int*)(ws + 105935376);
    unsigned int* recs    = (unsigned int*)(ws + 106095376);
    int*          bsum    = (int*)(ws + 109295376);

    hipMemsetAsync(deg, 0, (size_t)RR * NN * sizeof(int), stream);

    int ne = RR * EE;
    int ncast = NN * DD / 4 + DD * KTOT;
    k_cast<<<(ncast + 255) / 256, 256, 0, stream>>>(x, bases, lw, xb, Bt);
    k_deg<<<(ne + 255) / 256, 256, 0, stream>>>(edst, deg);
    k_hist<<<(NN + 255) / 256, 256, 0, stream>>>(deg, hist);
    k_scanA<<<SCAN_BLK, 256, 0, stream>>>(hist, offsets, bsum);
    k_scanB<<<SCAN_BLK, 256, 0, stream>>>(bsum, offsets, cursor);
    k_escatter<<<(ne + 255) / 256, 256, 0, stream>>>(esrc, edst, cursor, recs);
    k_gather<<<NN / 4, 256, 0, stream>>>(xb, coeff, deg, offsets, recs, vb);
    dim3 ggrid((NN + 127) / 128, 2);
    k_gemm<<<ggrid, 256, 0, stream>>>(vb, xb, Bt, bias, out);
}